// Round 15
// baseline (437.993 us; speedup 1.0000x reference)
//
#include <hip/hip_runtime.h>
#include <math.h>

#define NPATH 70656
#define NBATCH 512
#define OUTD 480
#define OUTSZ (OUTD*OUTD)   // 230400 per point
#define ZCHV_S 32           // stream z-chunk
#define ZCHV_T 32           // tiled z-chunk
#define ZTS 8               // stream z-tile
#define ZTT 8               // tiled z-tile (barrier granularity)

// c-region start offset per pair p = lo*3+li
// sizes: 16384,8192,4096 | 8192,12288,6144 | 4096,6144,5120
constexpr int CBEG_TAB[9] = {0,16384,24576,28672,36864,49152,55296,59392,65536};

struct QPtrs { const float* q[9]; };

// ---------------- Kernel A: spherical harmonics + h (z-major) ----------------
__global__ __launch_bounds__(256) void sh_mlp_kernel(
    const float* __restrict__ r, const float* __restrict__ w1,
    const float* __restrict__ b1, float* __restrict__ Yg,
    float* __restrict__ hTz)
{
  int z = blockIdx.x*256 + threadIdx.x;
  if (z >= NBATCH) return;
  float x = r[3*z], y = r[3*z+1], zz = r[3*z+2];
  float nrm = sqrtf(x*x + y*y + zz*zz);
  float inv = 1.0f / fmaxf(nrm, 1e-9f);
  float dx = x*inv, dy = y*inv, dz = zz*inv;
  float rxy = sqrtf(fmaxf(dx*dx + dy*dy, 1e-18f));
  float cphi = dx/rxy, sphi = dy/rxy;
  float somx2 = sqrtf(fmaxf(1.0f - dz*dz, 1e-12f));

  float P[5][5];
  float pmm = 1.0f;
  #pragma unroll
  for (int m = 0; m < 5; ++m) {
    if (m > 0) pmm *= (float)(2*m-1) * somx2;
    P[m][m] = pmm;
    if (m+1 < 5) P[m+1][m] = dz * (float)(2*m+1) * pmm;
    #pragma unroll
    for (int l = m+2; l < 5; ++l)
      P[l][m] = ((float)(2*l-1)*dz*P[l-1][m] - (float)(l+m-1)*P[l-2][m]) / (float)(l-m);
  }
  float cm[5], sm[5];
  cm[0]=1.0f; sm[0]=0.0f; cm[1]=cphi; sm[1]=sphi;
  #pragma unroll
  for (int m = 2; m < 5; ++m) {
    cm[m] = cm[m-1]*cphi - sm[m-1]*sphi;
    sm[m] = sm[m-1]*cphi + cm[m-1]*sphi;
  }
  const float fact[9] = {1,1,2,6,24,120,720,5040,40320};
  int row = 0;
  #pragma unroll
  for (int l = 0; l < 5; ++l) {
    #pragma unroll
    for (int m = -l; m <= l; ++m) {
      int am = m < 0 ? -m : m;
      float N = sqrtf((float)(2*l+1) / 12.566370614359172f * fact[l-am] / fact[l+am]);
      float v;
      if (m == 0)      v = N * P[l][0];
      else if (m > 0)  v = 1.4142135623730951f * N * P[l][am] * cm[am];
      else             v = 1.4142135623730951f * N * P[l][am] * sm[am];
      Yg[z*25 + row] = v;
      ++row;
    }
  }
  #pragma unroll
  for (int k = 0; k < 64; ++k)
    hTz[z*64 + k] = fmaxf(nrm * w1[k] + b1[k], 0.0f);
}

// ---------------- Streaming body: DJ==1 regions (identical to R11) ----------
template<int LO, int LI>
__device__ __forceinline__ void stream_body(
    int bidl, const float* __restrict__ Yg, const float* __restrict__ hTz,
    const float* __restrict__ w2f, const float* __restrict__ b2,
    const float* __restrict__ Q, float* __restrict__ out,
    float* h_lds, float* Y_lds)
{
  constexpr int DI = 2*LO+1, DJ = 2*LI+1;
  constexpr int MI = 128>>LI;
  constexpr int NUV = (128>>LO)*MI;
  constexpr int UVB = NUV/256;
  constexpr int LF = LO+LI;
  constexpr int MAXM = 2*LF+1;
  constexpr int ROWOFF = (LO==0)?0:((LO==1)?128:320);
  constexpr int COLOFF = (LI==0)?0:((LI==1)?128:320);
  constexpr int CBEG = CBEG_TAB[LO*3+LI];
  constexpr float NS = (LO==0)?224.0f:((LO==1)?416.0f:480.0f);
  const float xn = sqrtf((float)(2*LI+1) * 12.566370614359172f / NS);

  const int tid = threadIdx.x;
  const int uvb   = bidl % UVB;
  const int chunk = bidl / UVB;
  const int z0 = chunk * ZCHV_S;
  const int uv = uvb*256 + tid;
  const int uu = uv >> (7-LI);
  const int vv = uv & (MI-1);
  const int path = CBEG + uv;
  const float b2p = b2[path];

  // ---- stage h (coalesced float4) and Y for this z-chunk ----
  #pragma unroll
  for (int i = tid; i < ZCHV_S*16; i += 256)
    ((float4*)h_lds)[i] = ((const float4*)(hTz + (size_t)z0*64))[i];
  for (int i = tid; i < ZCHV_S*25; i += 256)
    Y_lds[i] = Yg[(size_t)z0*25 + i];
  __syncthreads();

  float Qv[DI*DJ][MAXM];
  #pragma unroll
  for (int ij = 0; ij < DI*DJ; ++ij)
    #pragma unroll
    for (int m = 0; m < MAXM; ++m)
      Qv[ij][m] = Q[ij*MAXM + m];

  float* outR = out + (size_t)(ROWOFF + uu*DI)*OUTD + COLOFF + vv*DJ;

  for (int t0 = 0; t0 < ZCHV_S; t0 += ZTS) {
    float acc[ZTS];
    #pragma unroll
    for (int zt = 0; zt < ZTS; ++zt) acc[zt] = b2p;
    #pragma unroll
    for (int kk = 0; kk < 64; kk += 16) {
      float w2c[16];
      #pragma unroll
      for (int k = 0; k < 16; ++k)
        w2c[k] = w2f[(size_t)(kk+k)*NPATH + path];   // lane-coalesced VMEM
      #pragma unroll
      for (int zt = 0; zt < ZTS; ++zt) {
        const float* hz = h_lds + (t0+zt)*64 + kk;    // LDS broadcast
        float h[16];
        #pragma unroll
        for (int q = 0; q < 16; q += 4) *(float4*)&h[q] = *(const float4*)(hz+q);
        float s0=0.f, s1=0.f, s2=0.f, s3=0.f;
        #pragma unroll
        for (int k = 0; k < 16; k += 4) {
          s0 = fmaf(h[k],   w2c[k],   s0);
          s1 = fmaf(h[k+1], w2c[k+1], s1);
          s2 = fmaf(h[k+2], w2c[k+2], s2);
          s3 = fmaf(h[k+3], w2c[k+3], s3);
        }
        acc[zt] += (s0+s1)+(s2+s3);
      }
    }
    #pragma unroll
    for (int zt = 0; zt < ZTS; ++zt) {
      const int zl = t0 + zt;
      const float* yz = Y_lds + zl*25 + LF*LF;        // LDS broadcast
      const float c = acc[zt]*xn;
      float* oz = outR + (size_t)(z0+zl)*OUTSZ;
      #pragma unroll
      for (int i = 0; i < DI; ++i)
        #pragma unroll
        for (int j = 0; j < DJ; ++j) {
          float a = 0.0f;
          #pragma unroll
          for (int m = 0; m < MAXM; ++m) a = fmaf(Qv[i*DJ+j][m], yz[m], a);
          oz[i*OUTD + j] = a*c;
        }
    }
  }
}

// ---------------- streamx body: (0,1),(0,2) — contiguous o-remapped stores --
// Old mapping stored at lane-stride DJ (3/5 floats) -> 3-5x store-transaction
// inflation. Here c goes through LDS (xn folded in) and the store phase is
// remapped so thread's s-th output is element tid+256*s of the contiguous
// region rows -> pure stride-1 wave stores. NOUT = 256*DJ exactly.
template<int LO, int LI>
__device__ __forceinline__ void streamx_body(
    int bidl, const float* __restrict__ Yg, const float* __restrict__ hTz,
    const float* __restrict__ w2f, const float* __restrict__ b2,
    const float* __restrict__ Q, float* __restrict__ out,
    float* h_lds, float* Y_lds, float* cx_lds)
{
  constexpr int DJ = 2*LI+1;
  constexpr int MI = 128>>LI;
  constexpr int NUV = 128*MI;            // LO==0
  constexpr int UVB = NUV/256;
  constexpr int R = 256/MI;              // uu rows per block (4 or 8)
  constexpr int W = MI*DJ;               // floats per region row (192 or 160)
  constexpr int LF = LI;
  constexpr int MAXM = 2*LF+1;
  constexpr int COLOFF = (LI==1)?128:320;
  constexpr int CBEG = CBEG_TAB[LI];     // LO==0 -> region index == LI
  const float xn = sqrtf((float)(2*LI+1) * 12.566370614359172f / 224.0f);

  const int tid = threadIdx.x;
  const int uvb   = bidl % UVB;
  const int chunk = bidl / UVB;
  const int z0 = chunk * ZCHV_S;
  const int uu0 = uvb * R;
  const int path = CBEG + uvb*256 + tid;
  const float b2p = b2[path];

  // ---- stage h and Y ----
  #pragma unroll
  for (int i = tid; i < ZCHV_S*16; i += 256)
    ((float4*)h_lds)[i] = ((const float4*)(hTz + (size_t)z0*64))[i];
  for (int i = tid; i < ZCHV_S*25; i += 256)
    Y_lds[i] = Yg[(size_t)z0*25 + i];
  __syncthreads();

  float Qv[DJ][MAXM];
  #pragma unroll
  for (int j = 0; j < DJ; ++j)
    #pragma unroll
    for (int m = 0; m < MAXM; ++m)
      Qv[j][m] = Q[j*MAXM + m];

  // o-decode hoisted out of all z loops (z-invariant)
  int ooff_o[DJ], cidx_o[DJ], j_o[DJ];
  #pragma unroll
  for (int s = 0; s < DJ; ++s) {
    int o = tid + 256*s;
    int rr = o / W, col = o - rr*W;
    int vv = col / DJ, j = col - vv*DJ;
    ooff_o[s] = (uu0 + rr)*OUTD + col;
    cidx_o[s] = rr*MI + vv;
    j_o[s] = j;
  }
  float* outB = out + COLOFF;

  for (int t0 = 0; t0 < ZCHV_S; t0 += ZTS) {
    float acc[ZTS];
    #pragma unroll
    for (int zt = 0; zt < ZTS; ++zt) acc[zt] = b2p;
    #pragma unroll
    for (int kk = 0; kk < 64; kk += 16) {
      float w2c[16];
      #pragma unroll
      for (int k = 0; k < 16; ++k)
        w2c[k] = w2f[(size_t)(kk+k)*NPATH + path];   // lane-coalesced VMEM
      #pragma unroll
      for (int zt = 0; zt < ZTS; ++zt) {
        const float* hz = h_lds + (t0+zt)*64 + kk;    // LDS broadcast
        float h[16];
        #pragma unroll
        for (int q = 0; q < 16; q += 4) *(float4*)&h[q] = *(const float4*)(hz+q);
        float s0=0.f, s1=0.f, s2=0.f, s3=0.f;
        #pragma unroll
        for (int k = 0; k < 16; k += 4) {
          s0 = fmaf(h[k],   w2c[k],   s0);
          s1 = fmaf(h[k+1], w2c[k+1], s1);
          s2 = fmaf(h[k+2], w2c[k+2], s2);
          s3 = fmaf(h[k+3], w2c[k+3], s3);
        }
        acc[zt] += (s0+s1)+(s2+s3);
      }
    }
    // WAR fence: previous store-phase LDS reads done before overwrite
    if (t0 > 0)
      asm volatile("s_waitcnt lgkmcnt(0)\n\ts_barrier" ::: "memory");
    #pragma unroll
    for (int zt = 0; zt < ZTS; ++zt) cx_lds[zt*256 + tid] = acc[zt]*xn;
    // ready fence: LDS writes visible; global stores NOT drained
    asm volatile("s_waitcnt lgkmcnt(0)\n\ts_barrier" ::: "memory");

    // ---- store phase: contiguous stride-1 wave stores ----
    for (int zt = 0; zt < ZTS; ++zt) {
      const int zl = t0 + zt;
      const float* yz = Y_lds + zl*25 + LF*LF;
      float a_all[DJ];
      #pragma unroll
      for (int j = 0; j < DJ; ++j) {
        float a = 0.0f;
        #pragma unroll
        for (int m = 0; m < MAXM; ++m) a = fmaf(Qv[j][m], yz[m], a);
        a_all[j] = a;
      }
      float* oz = outB + (size_t)(z0+zl)*OUTSZ;
      const float* cxz = cx_lds + zt*256;
      #pragma unroll
      for (int s = 0; s < DJ; ++s)
        oz[ooff_o[s]] = a_all[j_o[s]] * cxz[cidx_o[s]];
    }
  }
}

// ---------------- Tiled body: NL>1 regions (identical to R11) ---------------
template<int LO, int LI>
__device__ __forceinline__ void tiled_body(
    int bidl, const float* __restrict__ Yg, const float* __restrict__ hTz,
    const float* __restrict__ w2f, const float* __restrict__ b2,
    const float* __restrict__ Q, float* __restrict__ out,
    float* c_lds, float* A_lds, float* h_lds)
{
  constexpr int DI = 2*LO+1, DJ = 2*LI+1;
  constexpr int MO = 128>>LO, MI = 128>>LI;
  constexpr int NL = 2*((LO<LI)?LO:LI)+1;
  constexpr int LF0 = (LO>LI)?(LO-LI):(LI-LO);
  constexpr int QDIM = (LO+LI+1)*(LO+LI+1) - LF0*LF0;
  constexpr int NUV = MO*MI;
  constexpr int G = 256/NL;
  constexpr int UVB = (NUV + G - 1)/G;
  constexpr int NOUT = G*DI*DJ;
  constexpr int OPT = (NOUT + 255)/256;
  constexpr int ASIZE = DI*DJ*NL;            // <= 125
  constexpr int MAXM = 2*(LO+LI)+1;
  constexpr int ROWOFF = (LO==0)?0:((LO==1)?128:320);
  constexpr int COLOFF = (LI==0)?0:((LI==1)?128:320);
  constexpr int CBEG = CBEG_TAB[LO*3+LI];
  constexpr float NS = (LO==0)?224.0f:((LO==1)?416.0f:480.0f);
  const float xn = sqrtf((float)(2*LI+1) * 12.566370614359172f / NS);

  const int tid = threadIdx.x;
  const int uvb   = bidl % UVB;
  const int chunk = bidl / UVB;
  const int uv0 = uvb * G;
  const int z0  = chunk * ZCHV_T;

  const int gl = tid / NL;
  const int kf = tid % NL;
  const bool cact = (gl < G) && (uv0 + gl < NUV);
  const int path = CBEG + (cact ? ((uv0+gl)*NL + kf) : 0);
  const float b2p = b2[path];

  // ---- stage h for this z-chunk ----
  #pragma unroll
  for (int i = tid; i < ZCHV_T*16; i += 256)
    ((float4*)h_lds)[i] = ((const float4*)(hTz + (size_t)z0*64))[i];

  // A-phase setup: Q values z-invariant -> registers
  float Qv[MAXM];
  int yb = 0;
  {
    int t = (tid < ASIZE) ? tid : 0;
    int i  = t / (DJ*NL);
    int j  = (t / NL) % DJ;
    int kA = t % NL;
    int lf = LF0 + kA;
    int qoff = kA*(2*LF0 + kA);
    int mlim = 2*lf + 1;
    yb = lf*lf;
    #pragma unroll
    for (int m = 0; m < MAXM; ++m)
      Qv[m] = (m < mlim) ? Q[(i*DJ + j)*QDIM + qoff + m] : 0.0f;
  }

  // output addressing hoisted out of all z loops
  int rowoff_o[OPT], aidx_o[OPT], cidx_o[OPT];
  bool val_o[OPT];
  #pragma unroll
  for (int t = 0; t < OPT; ++t) {
    int o = tid + 256*t;
    bool v = o < NOUT;
    int oo = v ? o : 0;
    int i   = oo / (G*DJ);
    int rem = oo % (G*DJ);
    int g   = rem / DJ;
    int j   = rem % DJ;
    int uv  = uv0 + g;
    v = v && (uv < NUV);
    int uu = uv >> (7-LI);
    int vv = uv & (MI-1);
    rowoff_o[t] = (uu*DI + i)*OUTD + vv*DJ + j;
    aidx_o[t] = (i*DJ + j)*NL;
    cidx_o[t] = g*NL;
    val_o[t] = v;
  }
  __syncthreads();   // h_lds staged

  float* outR = out + ROWOFF*OUTD + COLOFF;

  for (int tile = 0; tile < ZCHV_T/ZTT; ++tile) {
    const int p = tile & 1;
    float* cb = c_lds + p*(ZTT*256);
    float* ab = A_lds + p*(ZTT*128);
    const int zb = z0 + tile*ZTT;

    // ---- c-phase: coalesced scalar w2 loads, LDS-broadcast h ----
    float acc[ZTT];
    #pragma unroll
    for (int zt = 0; zt < ZTT; ++zt) acc[zt] = b2p;
    #pragma unroll
    for (int kk = 0; kk < 64; kk += 16) {
      float w2c[16];
      #pragma unroll
      for (int k = 0; k < 16; ++k)
        w2c[k] = w2f[(size_t)(kk+k)*NPATH + path];   // lane-coalesced
      #pragma unroll
      for (int zt = 0; zt < ZTT; ++zt) {
        const float* hz = h_lds + (tile*ZTT+zt)*64 + kk;   // LDS broadcast
        float h[16];
        #pragma unroll
        for (int q = 0; q < 16; q += 4) *(float4*)&h[q] = *(const float4*)(hz+q);
        float s0=0.f, s1=0.f, s2=0.f, s3=0.f;
        #pragma unroll
        for (int k = 0; k < 16; k += 4) {
          s0 = fmaf(h[k],   w2c[k],   s0);
          s1 = fmaf(h[k+1], w2c[k+1], s1);
          s2 = fmaf(h[k+2], w2c[k+2], s2);
          s3 = fmaf(h[k+3], w2c[k+3], s3);
        }
        acc[zt] += (s0+s1)+(s2+s3);
      }
    }
    #pragma unroll
    for (int zt = 0; zt < ZTT; ++zt) cb[zt*256 + tid] = acc[zt];

    // ---- A-phase ----
    if (tid < ASIZE) {
      #pragma unroll
      for (int zt = 0; zt < ZTT; ++zt) {
        const float* yz = Yg + (size_t)(zb+zt)*25 + yb;
        float s = 0.0f;
        #pragma unroll
        for (int m = 0; m < MAXM; ++m) s = fmaf(Qv[m], yz[m], s);
        ab[zt*128 + tid] = s;
      }
    }
    // lgkm-only barrier: LDS writes complete; global stores NOT drained.
    asm volatile("s_waitcnt lgkmcnt(0)\n\ts_barrier" ::: "memory");

    // ---- out-phase: 8 z of stores, no syncs ----
    for (int zt = 0; zt < ZTT; ++zt) {
      float* oz = outR + (size_t)(zb+zt)*OUTSZ;
      const float* cbz = cb + zt*256;
      const float* abz = ab + zt*128;
      #pragma unroll
      for (int t = 0; t < OPT; ++t) {
        if (val_o[t]) {
          float s = 0.0f;
          #pragma unroll
          for (int k = 0; k < NL; ++k) s += abz[aidx_o[t] + k] * cbz[cidx_o[t] + k];
          oz[rowoff_o[t]] = s*xn;
        }
      }
    }
  }
}

// stream regions per chunk: (0,0)x64 (0,1)x32 (0,2)x16 (1,0)x32 (2,0)x16 = 160
__global__ __launch_bounds__(256) void tp_stream_kernel(
    const float* __restrict__ Yg, const float* __restrict__ hTz,
    const float* __restrict__ w2, const float* __restrict__ b2,
    QPtrs qp, float* __restrict__ out)
{
  __shared__ float h_lds[ZCHV_S*64];   // 8 KB
  __shared__ float Y_lds[ZCHV_S*25];   // 3.2 KB
  __shared__ float cx_lds[ZTS*256];    // 8 KB (streamx regions only)
  const int b = blockIdx.x;
  const int chunk = b / 160;
  const int r = b % 160;
  if      (r <  64) stream_body<0,0>(chunk*64 + r,      Yg,hTz,w2,b2,qp.q[0],out,h_lds,Y_lds);
  else if (r <  96) streamx_body<0,1>(chunk*32 + (r- 64),Yg,hTz,w2,b2,qp.q[1],out,h_lds,Y_lds,cx_lds);
  else if (r < 112) streamx_body<0,2>(chunk*16 + (r- 96),Yg,hTz,w2,b2,qp.q[2],out,h_lds,Y_lds,cx_lds);
  else if (r < 144) stream_body<1,0>(chunk*32 + (r-112),Yg,hTz,w2,b2,qp.q[3],out,h_lds,Y_lds);
  else              stream_body<2,0>(chunk*16 + (r-144),Yg,hTz,w2,b2,qp.q[6],out,h_lds,Y_lds);
}

// tiled regions per chunk: (1,1)x49 (1,2)x25 (2,1)x25 (2,2)x21 = 120
__global__ __launch_bounds__(256) void tp_tiled_kernel(
    const float* __restrict__ Yg, const float* __restrict__ hTz,
    const float* __restrict__ w2, const float* __restrict__ b2,
    QPtrs qp, float* __restrict__ out)
{
  __shared__ float c_lds[2*ZTT*256];   // 16 KB
  __shared__ float A_lds[2*ZTT*128];   // 8 KB
  __shared__ float h_lds[ZCHV_T*64];   // 8 KB
  const int b = blockIdx.x;
  const int chunk = b / 120;
  const int r = b % 120;
  if      (r <  49) tiled_body<1,1>(chunk*49 + r,      Yg,hTz,w2,b2,qp.q[4],out,c_lds,A_lds,h_lds);
  else if (r <  74) tiled_body<1,2>(chunk*25 + (r-49), Yg,hTz,w2,b2,qp.q[5],out,c_lds,A_lds,h_lds);
  else if (r <  99) tiled_body<2,1>(chunk*25 + (r-74), Yg,hTz,w2,b2,qp.q[7],out,c_lds,A_lds,h_lds);
  else              tiled_body<2,2>(chunk*21 + (r-99), Yg,hTz,w2,b2,qp.q[8],out,c_lds,A_lds,h_lds);
}

extern "C" void kernel_launch(void* const* d_in, const int* in_sizes, int n_in,
                              void* d_out, int out_size, void* d_ws, size_t ws_size,
                              hipStream_t stream)
{
  (void)in_sizes; (void)n_in; (void)out_size; (void)ws_size;
  const float* r  = (const float*)d_in[0];
  const float* w1 = (const float*)d_in[1];
  const float* b1 = (const float*)d_in[2];
  const float* w2 = (const float*)d_in[3];
  const float* b2 = (const float*)d_in[4];
  float* out = (float*)d_out;

  float* ws  = (float*)d_ws;
  float* Yg  = ws;             // 512*25 = 12800 floats
  float* hTz = ws + 12800;     // 512*64 = 32768 floats

  QPtrs qp;
  for (int i = 0; i < 9; ++i) qp.q[i] = (const float*)d_in[5 + i];

  hipLaunchKernelGGL(sh_mlp_kernel, dim3(2), dim3(256), 0, stream, r, w1, b1, Yg, hTz);
  hipLaunchKernelGGL(tp_tiled_kernel,  dim3((NBATCH/ZCHV_T)*120), dim3(256), 0, stream,
                     Yg, hTz, w2, b2, qp, out);
  hipLaunchKernelGGL(tp_stream_kernel, dim3((NBATCH/ZCHV_S)*160), dim3(256), 0, stream,
                     Yg, hTz, w2, b2, qp, out);
}

// Round 16
// 177.002 us; speedup vs baseline: 2.4745x; 2.4745x over previous
//
#include <hip/hip_runtime.h>
#include <math.h>

#define NPATH 70656
#define NBATCH 512
#define OUTD 480
#define OUTSZ (OUTD*OUTD)   // 230400 per point
#define ZCHV_S 32           // stream z-chunk
#define ZCHV_T 32           // tiled z-chunk
#define ZTS 8               // stream z-tile
#define ZTT 8               // tiled z-tile (barrier granularity)

// c-region start offset per pair p = lo*3+li
// sizes: 16384,8192,4096 | 8192,12288,6144 | 4096,6144,5120
constexpr int CBEG_TAB[9] = {0,16384,24576,28672,36864,49152,55296,59392,65536};

struct QPtrs { const float* q[9]; };

// ---------------- Kernel A: spherical harmonics + h (z-major) ----------------
__global__ __launch_bounds__(256) void sh_mlp_kernel(
    const float* __restrict__ r, const float* __restrict__ w1,
    const float* __restrict__ b1, float* __restrict__ Yg,
    float* __restrict__ hTz)
{
  int z = blockIdx.x*256 + threadIdx.x;
  if (z >= NBATCH) return;
  float x = r[3*z], y = r[3*z+1], zz = r[3*z+2];
  float nrm = sqrtf(x*x + y*y + zz*zz);
  float inv = 1.0f / fmaxf(nrm, 1e-9f);
  float dx = x*inv, dy = y*inv, dz = zz*inv;
  float rxy = sqrtf(fmaxf(dx*dx + dy*dy, 1e-18f));
  float cphi = dx/rxy, sphi = dy/rxy;
  float somx2 = sqrtf(fmaxf(1.0f - dz*dz, 1e-12f));

  float P[5][5];
  float pmm = 1.0f;
  #pragma unroll
  for (int m = 0; m < 5; ++m) {
    if (m > 0) pmm *= (float)(2*m-1) * somx2;
    P[m][m] = pmm;
    if (m+1 < 5) P[m+1][m] = dz * (float)(2*m+1) * pmm;
    #pragma unroll
    for (int l = m+2; l < 5; ++l)
      P[l][m] = ((float)(2*l-1)*dz*P[l-1][m] - (float)(l+m-1)*P[l-2][m]) / (float)(l-m);
  }
  float cm[5], sm[5];
  cm[0]=1.0f; sm[0]=0.0f; cm[1]=cphi; sm[1]=sphi;
  #pragma unroll
  for (int m = 2; m < 5; ++m) {
    cm[m] = cm[m-1]*cphi - sm[m-1]*sphi;
    sm[m] = sm[m-1]*cphi + cm[m-1]*sphi;
  }
  const float fact[9] = {1,1,2,6,24,120,720,5040,40320};
  int row = 0;
  #pragma unroll
  for (int l = 0; l < 5; ++l) {
    #pragma unroll
    for (int m = -l; m <= l; ++m) {
      int am = m < 0 ? -m : m;
      float N = sqrtf((float)(2*l+1) / 12.566370614359172f * fact[l-am] / fact[l+am]);
      float v;
      if (m == 0)      v = N * P[l][0];
      else if (m > 0)  v = 1.4142135623730951f * N * P[l][am] * cm[am];
      else             v = 1.4142135623730951f * N * P[l][am] * sm[am];
      Yg[z*25 + row] = v;
      ++row;
    }
  }
  #pragma unroll
  for (int k = 0; k < 64; ++k)
    hTz[z*64 + k] = fmaxf(nrm * w1[k] + b1[k], 0.0f);
}

// ---------------- Streaming body: DJ==1 regions (identical to R11) ----------
// Lane-stride-1 stores already; c in registers, no LDS exchange, no barriers.
template<int LO, int LI>
__device__ __forceinline__ void stream_body(
    int bidl, const float* __restrict__ Yg, const float* __restrict__ hTz,
    const float* __restrict__ w2f, const float* __restrict__ b2,
    const float* __restrict__ Q, float* __restrict__ out,
    float* h_lds, float* Y_lds)
{
  constexpr int DI = 2*LO+1, DJ = 2*LI+1;
  constexpr int MI = 128>>LI;
  constexpr int NUV = (128>>LO)*MI;
  constexpr int UVB = NUV/256;
  constexpr int LF = LO+LI;
  constexpr int MAXM = 2*LF+1;
  constexpr int ROWOFF = (LO==0)?0:((LO==1)?128:320);
  constexpr int COLOFF = (LI==0)?0:((LI==1)?128:320);
  constexpr int CBEG = CBEG_TAB[LO*3+LI];
  constexpr float NS = (LO==0)?224.0f:((LO==1)?416.0f:480.0f);
  const float xn = sqrtf((float)(2*LI+1) * 12.566370614359172f / NS);

  const int tid = threadIdx.x;
  const int uvb   = bidl % UVB;
  const int chunk = bidl / UVB;
  const int z0 = chunk * ZCHV_S;
  const int uv = uvb*256 + tid;
  const int uu = uv >> (7-LI);
  const int vv = uv & (MI-1);
  const int path = CBEG + uv;
  const float b2p = b2[path];

  // ---- stage h (coalesced float4) and Y for this z-chunk ----
  #pragma unroll
  for (int i = tid; i < ZCHV_S*16; i += 256)
    ((float4*)h_lds)[i] = ((const float4*)(hTz + (size_t)z0*64))[i];
  for (int i = tid; i < ZCHV_S*25; i += 256)
    Y_lds[i] = Yg[(size_t)z0*25 + i];
  __syncthreads();

  float Qv[DI*DJ][MAXM];
  #pragma unroll
  for (int ij = 0; ij < DI*DJ; ++ij)
    #pragma unroll
    for (int m = 0; m < MAXM; ++m)
      Qv[ij][m] = Q[ij*MAXM + m];

  float* outR = out + (size_t)(ROWOFF + uu*DI)*OUTD + COLOFF + vv*DJ;

  for (int t0 = 0; t0 < ZCHV_S; t0 += ZTS) {
    float acc[ZTS];
    #pragma unroll
    for (int zt = 0; zt < ZTS; ++zt) acc[zt] = b2p;
    #pragma unroll
    for (int kk = 0; kk < 64; kk += 16) {
      float w2c[16];
      #pragma unroll
      for (int k = 0; k < 16; ++k)
        w2c[k] = w2f[(size_t)(kk+k)*NPATH + path];   // lane-coalesced VMEM
      #pragma unroll
      for (int zt = 0; zt < ZTS; ++zt) {
        const float* hz = h_lds + (t0+zt)*64 + kk;    // LDS broadcast
        float h[16];
        #pragma unroll
        for (int q = 0; q < 16; q += 4) *(float4*)&h[q] = *(const float4*)(hz+q);
        float s0=0.f, s1=0.f, s2=0.f, s3=0.f;
        #pragma unroll
        for (int k = 0; k < 16; k += 4) {
          s0 = fmaf(h[k],   w2c[k],   s0);
          s1 = fmaf(h[k+1], w2c[k+1], s1);
          s2 = fmaf(h[k+2], w2c[k+2], s2);
          s3 = fmaf(h[k+3], w2c[k+3], s3);
        }
        acc[zt] += (s0+s1)+(s2+s3);
      }
    }
    #pragma unroll
    for (int zt = 0; zt < ZTS; ++zt) {
      const int zl = t0 + zt;
      const float* yz = Y_lds + zl*25 + LF*LF;        // LDS broadcast
      const float c = acc[zt]*xn;
      float* oz = outR + (size_t)(z0+zl)*OUTSZ;
      #pragma unroll
      for (int i = 0; i < DI; ++i)
        #pragma unroll
        for (int j = 0; j < DJ; ++j) {
          float a = 0.0f;
          #pragma unroll
          for (int m = 0; m < MAXM; ++m) a = fmaf(Qv[i*DJ+j][m], yz[m], a);
          oz[i*OUTD + j] = a*c;
        }
    }
  }
}

// ---------------- Tiled body (identical to R11) ------------------------------
// Handles all regions needing c-exchange for coalesced stores. For NL==1
// regions ((0,1),(0,2)) it degenerates cleanly: G=256, no masking, ASIZE=DJ,
// and the out-phase's o = tid+256*t mapping gives stride-1 wave stores —
// exactly the fix for the 3x/5x store-transaction inflation those regions
// had in stream_body (R15 counters: 338 vs 268 MB write).
template<int LO, int LI>
__device__ __forceinline__ void tiled_body(
    int bidl, const float* __restrict__ Yg, const float* __restrict__ hTz,
    const float* __restrict__ w2f, const float* __restrict__ b2,
    const float* __restrict__ Q, float* __restrict__ out,
    float* c_lds, float* A_lds, float* h_lds)
{
  constexpr int DI = 2*LO+1, DJ = 2*LI+1;
  constexpr int MO = 128>>LO, MI = 128>>LI;
  constexpr int NL = 2*((LO<LI)?LO:LI)+1;
  constexpr int LF0 = (LO>LI)?(LO-LI):(LI-LO);
  constexpr int QDIM = (LO+LI+1)*(LO+LI+1) - LF0*LF0;
  constexpr int NUV = MO*MI;
  constexpr int G = 256/NL;
  constexpr int UVB = (NUV + G - 1)/G;
  constexpr int NOUT = G*DI*DJ;
  constexpr int OPT = (NOUT + 255)/256;
  constexpr int ASIZE = DI*DJ*NL;            // <= 125
  constexpr int MAXM = 2*(LO+LI)+1;
  constexpr int ROWOFF = (LO==0)?0:((LO==1)?128:320);
  constexpr int COLOFF = (LI==0)?0:((LI==1)?128:320);
  constexpr int CBEG = CBEG_TAB[LO*3+LI];
  constexpr float NS = (LO==0)?224.0f:((LO==1)?416.0f:480.0f);
  const float xn = sqrtf((float)(2*LI+1) * 12.566370614359172f / NS);

  const int tid = threadIdx.x;
  const int uvb   = bidl % UVB;
  const int chunk = bidl / UVB;
  const int uv0 = uvb * G;
  const int z0  = chunk * ZCHV_T;

  const int gl = tid / NL;
  const int kf = tid % NL;
  const bool cact = (gl < G) && (uv0 + gl < NUV);
  const int path = CBEG + (cact ? ((uv0+gl)*NL + kf) : 0);
  const float b2p = b2[path];

  // ---- stage h for this z-chunk ----
  #pragma unroll
  for (int i = tid; i < ZCHV_T*16; i += 256)
    ((float4*)h_lds)[i] = ((const float4*)(hTz + (size_t)z0*64))[i];

  // A-phase setup: Q values z-invariant -> registers
  float Qv[MAXM];
  int yb = 0;
  {
    int t = (tid < ASIZE) ? tid : 0;
    int i  = t / (DJ*NL);
    int j  = (t / NL) % DJ;
    int kA = t % NL;
    int lf = LF0 + kA;
    int qoff = kA*(2*LF0 + kA);
    int mlim = 2*lf + 1;
    yb = lf*lf;
    #pragma unroll
    for (int m = 0; m < MAXM; ++m)
      Qv[m] = (m < mlim) ? Q[(i*DJ + j)*QDIM + qoff + m] : 0.0f;
  }

  // output addressing hoisted out of all z loops
  int rowoff_o[OPT], aidx_o[OPT], cidx_o[OPT];
  bool val_o[OPT];
  #pragma unroll
  for (int t = 0; t < OPT; ++t) {
    int o = tid + 256*t;
    bool v = o < NOUT;
    int oo = v ? o : 0;
    int i   = oo / (G*DJ);
    int rem = oo % (G*DJ);
    int g   = rem / DJ;
    int j   = rem % DJ;
    int uv  = uv0 + g;
    v = v && (uv < NUV);
    int uu = uv >> (7-LI);
    int vv = uv & (MI-1);
    rowoff_o[t] = (uu*DI + i)*OUTD + vv*DJ + j;
    aidx_o[t] = (i*DJ + j)*NL;
    cidx_o[t] = g*NL;
    val_o[t] = v;
  }
  __syncthreads();   // h_lds staged

  float* outR = out + ROWOFF*OUTD + COLOFF;

  for (int tile = 0; tile < ZCHV_T/ZTT; ++tile) {
    const int p = tile & 1;
    float* cb = c_lds + p*(ZTT*256);
    float* ab = A_lds + p*(ZTT*128);
    const int zb = z0 + tile*ZTT;

    // ---- c-phase: coalesced scalar w2 loads, LDS-broadcast h ----
    float acc[ZTT];
    #pragma unroll
    for (int zt = 0; zt < ZTT; ++zt) acc[zt] = b2p;
    #pragma unroll
    for (int kk = 0; kk < 64; kk += 16) {
      float w2c[16];
      #pragma unroll
      for (int k = 0; k < 16; ++k)
        w2c[k] = w2f[(size_t)(kk+k)*NPATH + path];   // lane-coalesced
      #pragma unroll
      for (int zt = 0; zt < ZTT; ++zt) {
        const float* hz = h_lds + (tile*ZTT+zt)*64 + kk;   // LDS broadcast
        float h[16];
        #pragma unroll
        for (int q = 0; q < 16; q += 4) *(float4*)&h[q] = *(const float4*)(hz+q);
        float s0=0.f, s1=0.f, s2=0.f, s3=0.f;
        #pragma unroll
        for (int k = 0; k < 16; k += 4) {
          s0 = fmaf(h[k],   w2c[k],   s0);
          s1 = fmaf(h[k+1], w2c[k+1], s1);
          s2 = fmaf(h[k+2], w2c[k+2], s2);
          s3 = fmaf(h[k+3], w2c[k+3], s3);
        }
        acc[zt] += (s0+s1)+(s2+s3);
      }
    }
    #pragma unroll
    for (int zt = 0; zt < ZTT; ++zt) cb[zt*256 + tid] = acc[zt];

    // ---- A-phase ----
    if (tid < ASIZE) {
      #pragma unroll
      for (int zt = 0; zt < ZTT; ++zt) {
        const float* yz = Yg + (size_t)(zb+zt)*25 + yb;
        float s = 0.0f;
        #pragma unroll
        for (int m = 0; m < MAXM; ++m) s = fmaf(Qv[m], yz[m], s);
        ab[zt*128 + tid] = s;
      }
    }
    // lgkm-only barrier: LDS writes complete; global stores NOT drained.
    asm volatile("s_waitcnt lgkmcnt(0)\n\ts_barrier" ::: "memory");

    // ---- out-phase: 8 z of stores, no syncs ----
    for (int zt = 0; zt < ZTT; ++zt) {
      float* oz = outR + (size_t)(zb+zt)*OUTSZ;
      const float* cbz = cb + zt*256;
      const float* abz = ab + zt*128;
      #pragma unroll
      for (int t = 0; t < OPT; ++t) {
        if (val_o[t]) {
          float s = 0.0f;
          #pragma unroll
          for (int k = 0; k < NL; ++k) s += abz[aidx_o[t] + k] * cbz[cidx_o[t] + k];
          oz[rowoff_o[t]] = s*xn;
        }
      }
    }
  }
}

// stream regions per chunk (DJ==1 only): (0,0)x64 (1,0)x32 (2,0)x16 = 112
__global__ __launch_bounds__(256) void tp_stream_kernel(
    const float* __restrict__ Yg, const float* __restrict__ hTz,
    const float* __restrict__ w2, const float* __restrict__ b2,
    QPtrs qp, float* __restrict__ out)
{
  __shared__ float h_lds[ZCHV_S*64];   // 8 KB
  __shared__ float Y_lds[ZCHV_S*25];   // 3.2 KB
  const int b = blockIdx.x;
  const int chunk = b / 112;
  const int r = b % 112;
  if      (r <  64) stream_body<0,0>(chunk*64 + r,      Yg,hTz,w2,b2,qp.q[0],out,h_lds,Y_lds);
  else if (r <  96) stream_body<1,0>(chunk*32 + (r-64), Yg,hTz,w2,b2,qp.q[3],out,h_lds,Y_lds);
  else              stream_body<2,0>(chunk*16 + (r-96), Yg,hTz,w2,b2,qp.q[6],out,h_lds,Y_lds);
}

// tiled regions per chunk: (1,1)x49 (1,2)x25 (2,1)x25 (2,2)x21 (0,1)x32 (0,2)x16 = 168
__global__ __launch_bounds__(256) void tp_tiled_kernel(
    const float* __restrict__ Yg, const float* __restrict__ hTz,
    const float* __restrict__ w2, const float* __restrict__ b2,
    QPtrs qp, float* __restrict__ out)
{
  __shared__ float c_lds[2*ZTT*256];   // 16 KB
  __shared__ float A_lds[2*ZTT*128];   // 8 KB
  __shared__ float h_lds[ZCHV_T*64];   // 8 KB
  const int b = blockIdx.x;
  const int chunk = b / 168;
  const int r = b % 168;
  if      (r <  49) tiled_body<1,1>(chunk*49 + r,       Yg,hTz,w2,b2,qp.q[4],out,c_lds,A_lds,h_lds);
  else if (r <  74) tiled_body<1,2>(chunk*25 + (r-49),  Yg,hTz,w2,b2,qp.q[5],out,c_lds,A_lds,h_lds);
  else if (r <  99) tiled_body<2,1>(chunk*25 + (r-74),  Yg,hTz,w2,b2,qp.q[7],out,c_lds,A_lds,h_lds);
  else if (r < 120) tiled_body<2,2>(chunk*21 + (r-99),  Yg,hTz,w2,b2,qp.q[8],out,c_lds,A_lds,h_lds);
  else if (r < 152) tiled_body<0,1>(chunk*32 + (r-120), Yg,hTz,w2,b2,qp.q[1],out,c_lds,A_lds,h_lds);
  else              tiled_body<0,2>(chunk*16 + (r-152), Yg,hTz,w2,b2,qp.q[2],out,c_lds,A_lds,h_lds);
}

extern "C" void kernel_launch(void* const* d_in, const int* in_sizes, int n_in,
                              void* d_out, int out_size, void* d_ws, size_t ws_size,
                              hipStream_t stream)
{
  (void)in_sizes; (void)n_in; (void)out_size; (void)ws_size;
  const float* r  = (const float*)d_in[0];
  const float* w1 = (const float*)d_in[1];
  const float* b1 = (const float*)d_in[2];
  const float* w2 = (const float*)d_in[3];
  const float* b2 = (const float*)d_in[4];
  float* out = (float*)d_out;

  float* ws  = (float*)d_ws;
  float* Yg  = ws;             // 512*25 = 12800 floats
  float* hTz = ws + 12800;     // 512*64 = 32768 floats

  QPtrs qp;
  for (int i = 0; i < 9; ++i) qp.q[i] = (const float*)d_in[5 + i];

  hipLaunchKernelGGL(sh_mlp_kernel, dim3(2), dim3(256), 0, stream, r, w1, b1, Yg, hTz);
  hipLaunchKernelGGL(tp_tiled_kernel,  dim3((NBATCH/ZCHV_T)*168), dim3(256), 0, stream,
                     Yg, hTz, w2, b2, qp, out);
  hipLaunchKernelGGL(tp_stream_kernel, dim3((NBATCH/ZCHV_S)*112), dim3(256), 0, stream,
                     Yg, hTz, w2, b2, qp, out);
}